// Round 4
// baseline (353.373 us; speedup 1.0000x reference)
//
#include <hip/hip_runtime.h>
#include <stdint.h>

// Problem constants
#define B_SZ 1024
#define Z_SZ 32768
#define D_SZ 128
#define TZ   64                 // z per inner tile
#define TBLK 64                 // batch rows per block (4 waves x 16)
#define WROWS 16

typedef short bf16x8 __attribute__((ext_vector_type(8)));
typedef float f32x4  __attribute__((ext_vector_type(4)));

__device__ __forceinline__ unsigned short f2bf(float f) {
    union { float f; uint32_t u; } v; v.f = f;
    uint32_t u = v.u;
    u = (u + 0x7FFFu + ((u >> 16) & 1u)) >> 16;   // RNE truncate to bf16
    return (unsigned short)u;
}

// ---- pack z_sparse>0 into bits [B][Z/32] + per-(row,wave) popcounts [B][4] ----
// Pure streaming read of the 134 MB input: coalesced dword loads + __ballot.
__global__ __launch_bounds__(256) void pack_mask(
    const int* __restrict__ zs, unsigned* __restrict__ pk, int* __restrict__ cntp)
{
    const int b    = blockIdx.x;
    const int wave = threadIdx.x >> 6;
    const int lane = threadIdx.x & 63;
    const int zw   = wave * (Z_SZ / 4);          // 8192 z per wave
    const int* row = zs + (size_t)b * Z_SZ + zw;
    unsigned* prow = pk + (size_t)b * (Z_SZ / 32) + (zw >> 5);
    int cnt = 0;
#pragma unroll 2
    for (int it = 0; it < (Z_SZ / 4) / 256; ++it) {   // 32 iters x 256 z
        int v0 = row[it * 256 + lane];
        int v1 = row[it * 256 +  64 + lane];
        int v2 = row[it * 256 + 128 + lane];
        int v3 = row[it * 256 + 192 + lane];
        unsigned long long w0 = __ballot(v0 > 0);     // bit l <-> z = base + l (natural order)
        unsigned long long w1 = __ballot(v1 > 0);
        unsigned long long w2 = __ballot(v2 > 0);
        unsigned long long w3 = __ballot(v3 > 0);
        cnt += __popcll(w0) + __popcll(w1) + __popcll(w2) + __popcll(w3);
        if (lane < 8) {                               // 8 u32 words per 256 z
            unsigned long long wa = (lane < 4) ? ((lane < 2) ? w0 : w1)
                                               : ((lane < 6) ? w2 : w3);
            unsigned v32 = (lane & 1) ? (unsigned)(wa >> 32) : (unsigned)wa;
            prow[it * 8 + lane] = v32;
        }
    }
    if (lane == 0) cntp[b * 4 + wave] = cnt;
}

// ---- one-shot fp32 -> bf16: embB row-major [Z][128]; embT2 blocked-transposed [Z/64][128][64] ----
__global__ __launch_bounds__(256) void convert_emb(
    const float* __restrict__ emb,
    unsigned short* __restrict__ embB,
    unsigned short* __restrict__ embT2)
{
    __shared__ unsigned short s[128 * 68];
    const int tid = threadIdx.x;
    const int z0  = blockIdx.x * 64;
    const int zl  = tid >> 2;
    const int ds  = (tid & 3) * 32;
    const float* src = emb + (size_t)(z0 + zl) * D_SZ + ds;
    unsigned short* dstB = embB + (size_t)(z0 + zl) * D_SZ + ds;
#pragma unroll
    for (int u = 0; u < 8; ++u) {
        float4 x = *(const float4*)(src + 4 * u);
        ushort4 h; h.x = f2bf(x.x); h.y = f2bf(x.y); h.z = f2bf(x.z); h.w = f2bf(x.w);
        *(ushort4*)(dstB + 4 * u) = h;
        s[(ds + 4*u + 0) * 68 + zl] = h.x;
        s[(ds + 4*u + 1) * 68 + zl] = h.y;
        s[(ds + 4*u + 2) * 68 + zl] = h.z;
        s[(ds + 4*u + 3) * 68 + zl] = h.w;
    }
    __syncthreads();
    const int d  = tid & 127;
    const int zh = (tid >> 7) * 32;
    unsigned short* dstT = embT2 + (size_t)blockIdx.x * (128 * 64) + d * 64 + zh;
    const unsigned short* srow = s + d * 68 + zh;
#pragma unroll
    for (int u = 0; u < 8; ++u)
        *(ushort4*)(dstT + 4 * u) = *(const ushort4*)(srow + 4 * u);
}

// ---- flash-style partial kernel: LDS tiles, XOR-swizzled, packed bitmasks ----
// grid (nz, 16): chunk varies fastest -> chunk ch pinned to XCD ch%8 -> 2 MB table slice per XCD L2
__global__ __launch_bounds__(256, 4) void attn_part(
    const unsigned long long* __restrict__ pk64,
    const float*              __restrict__ ctx,
    const unsigned short*     __restrict__ embB,
    const unsigned short*     __restrict__ embT2,
    float* __restrict__ mbuf, float* __restrict__ lbuf,
    float* __restrict__ obuf, int iters)
{
    __shared__ __align__(16) unsigned short s_all[20480];   // 40960 B -> 4 blocks/CU

    const int tid  = threadIdx.x;
    const int wave = tid >> 6;
    const int lane = tid & 63;
    const int l15  = lane & 15;
    const int quad = lane >> 4;

    const int ch     = blockIdx.x;
    const int bg     = blockIdx.y;
    const int cz     = iters * TZ;
    const int z_base = ch * cz;
    const int wb0    = bg * TBLK + wave * WROWS;

    // ---- ctx A-fragments (scaled), in registers whole kernel ----
    bf16x8 afrag[4];
    {
        const float scale = 0.08838834764831845f;  // 1/sqrt(128)
        const float* crow = ctx + (size_t)(wb0 + l15) * D_SZ;
#pragma unroll
        for (int ks = 0; ks < 4; ++ks) {
            const float* p = crow + ks * 32 + quad * 8;
            float4 x0 = *(const float4*)(p);
            float4 x1 = *(const float4*)(p + 4);
            bf16x8 a;
            a[0] = (short)f2bf(x0.x * scale); a[1] = (short)f2bf(x0.y * scale);
            a[2] = (short)f2bf(x0.z * scale); a[3] = (short)f2bf(x0.w * scale);
            a[4] = (short)f2bf(x1.x * scale); a[5] = (short)f2bf(x1.y * scale);
            a[6] = (short)f2bf(x1.z * scale); a[7] = (short)f2bf(x1.w * scale);
            afrag[ks] = a;
        }
    }

    float m_r[4], l_r[4];
    f32x4 acc2[8];
#pragma unroll
    for (int r = 0; r < 4; ++r) { m_r[r] = -1e30f; l_r[r] = 0.f; }
#pragma unroll
    for (int n = 0; n < 8; ++n) { acc2[n][0]=0.f; acc2[n][1]=0.f; acc2[n][2]=0.f; acc2[n][3]=0.f; }

    unsigned short* pw = s_all + 16384 + wave * 1024;

    for (int it = 0; it < iters; ++it) {
        const int z0 = z_base + it * TZ;

        __syncthreads();

        // ---- stage s_emb (16 KB contiguous) ----
#pragma unroll
        for (int k = 0; k < 4; ++k) {
            int c   = tid + 256 * k;
            int row = c >> 4, lseg = c & 15;
            bf16x8 v = *(const bf16x8*)(embB + ((size_t)(z0 + row) << 7) + (lseg << 3));
            int phys = lseg ^ (row & 15);
            *(bf16x8*)(s_all + (row << 7) + (phys << 3)) = v;
        }
        // ---- stage s_embT from blocked table (16 KB contiguous) ----
        {
            const unsigned short* tbase = embT2 + ((size_t)(z0 >> 6)) * (128 * 64);
#pragma unroll
            for (int k = 0; k < 4; ++k) {
                int c = tid + 256 * k;
                int d = c >> 3, lseg = c & 7;
                bf16x8 v = *(const bf16x8*)(tbase + ((size_t)c << 3));
                int phys = lseg ^ (d & 7);
                *(bf16x8*)(s_all + 8192 + (d << 6) + (phys << 3)) = v;
            }
        }

        // ---- packed masks: one broadcast u64 per row (L1-resident, 4 KB/block slice) ----
        unsigned mbits[4];
#pragma unroll
        for (int r = 0; r < 4; ++r) {
            unsigned long long W =
                pk64[(size_t)(wb0 + quad * 4 + r) * (Z_SZ / 64) + (z0 >> 6)];
            mbits[r] = ((unsigned)(W >>  l15)        & 1u)
                     | (((unsigned)(W >> (16 + l15)) & 1u) << 1)
                     | (((unsigned)(W >> (32 + l15)) & 1u) << 2)
                     | (((unsigned)(W >> (48 + l15)) & 1u) << 3);
        }

        __syncthreads();

        // ---- GEMM1: S[16x64] = ctx @ emb_tile^T (K=128) ----
        f32x4 sfr[4];
#pragma unroll
        for (int nt = 0; nt < 4; ++nt) {
            f32x4 c; c[0]=0.f; c[1]=0.f; c[2]=0.f; c[3]=0.f;
            const unsigned short* bb = s_all + ((nt * 16 + l15) << 7);
#pragma unroll
            for (int ks = 0; ks < 4; ++ks) {
                int phys = ((ks << 2) | quad) ^ l15;
                bf16x8 bf = *(const bf16x8*)(bb + (phys << 3));
                c = __builtin_amdgcn_mfma_f32_16x16x32_bf16(afrag[ks], bf, c, 0, 0, 0);
            }
            sfr[nt] = c;
        }

        // ---- masked online softmax ----
        float tmax[4];
#pragma unroll
        for (int r = 0; r < 4; ++r) {
            float a0 = (mbits[r] & 1u) ? sfr[0][r] : -1e30f;
            float a1 = (mbits[r] & 2u) ? sfr[1][r] : -1e30f;
            float a2 = (mbits[r] & 4u) ? sfr[2][r] : -1e30f;
            float a3 = (mbits[r] & 8u) ? sfr[3][r] : -1e30f;
            tmax[r] = fmaxf(fmaxf(a0, a1), fmaxf(a2, a3));
        }
#pragma unroll
        for (int s = 1; s < 16; s <<= 1) {
#pragma unroll
            for (int r = 0; r < 4; ++r) tmax[r] = fmaxf(tmax[r], __shfl_xor(tmax[r], s));
        }
        float alpha[4];
#pragma unroll
        for (int r = 0; r < 4; ++r) {
            float mnew = fmaxf(m_r[r], tmax[r]);
            alpha[r] = __expf(m_r[r] - mnew);
            m_r[r] = mnew;
            l_r[r] *= alpha[r];
        }
        float psum[4]; psum[0]=0.f; psum[1]=0.f; psum[2]=0.f; psum[3]=0.f;
#pragma unroll
        for (int nt = 0; nt < 4; ++nt) {
#pragma unroll
            for (int r = 0; r < 4; ++r) {
                float p = ((mbits[r] >> nt) & 1u) ? __expf(sfr[nt][r] - m_r[r]) : 0.f;
                psum[r] += p;
                int row  = quad * 4 + r;
                int seg  = nt * 2 + (l15 >> 3);
                int phys = seg ^ (row & 7);
                pw[(row << 6) + (phys << 3) + (l15 & 7)] = f2bf(p);
            }
        }
#pragma unroll
        for (int s = 1; s < 16; s <<= 1) {
#pragma unroll
            for (int r = 0; r < 4; ++r) psum[r] += __shfl_xor(psum[r], s);
        }
#pragma unroll
        for (int r = 0; r < 4; ++r) l_r[r] += psum[r];

#pragma unroll
        for (int n = 0; n < 8; ++n) {
#pragma unroll
            for (int r = 0; r < 4; ++r) acc2[n][r] *= alpha[r];
        }

        // ---- GEMM2: O[16x128] += P[16x64] @ emb_tile[64x128] ----
        const unsigned short* pb = pw + (l15 << 6);
        const int x0 = ( quad      ^ (l15 & 7)) << 3;
        const int x1 = ((quad + 4) ^ (l15 & 7)) << 3;
        bf16x8 pA0 = *(const bf16x8*)(pb + x0);
        bf16x8 pA1 = *(const bf16x8*)(pb + x1);
#pragma unroll
        for (int nt2 = 0; nt2 < 8; ++nt2) {
            const unsigned short* tb = s_all + 8192 + ((nt2 * 16 + l15) << 6);
            bf16x8 b0 = *(const bf16x8*)(tb + x0);
            bf16x8 b1 = *(const bf16x8*)(tb + x1);
            acc2[nt2] = __builtin_amdgcn_mfma_f32_16x16x32_bf16(pA0, b0, acc2[nt2], 0, 0, 0);
            acc2[nt2] = __builtin_amdgcn_mfma_f32_16x16x32_bf16(pA1, b1, acc2[nt2], 0, 0, 0);
        }
    }

    // ---- epilogue ----
#pragma unroll
    for (int nt2 = 0; nt2 < 8; ++nt2) {
#pragma unroll
        for (int r = 0; r < 4; ++r) {
            const int b = wb0 + quad * 4 + r;
            obuf[((size_t)ch * B_SZ + b) * D_SZ + nt2 * 16 + l15] = acc2[nt2][r];
        }
    }
    if (l15 == 0) {
#pragma unroll
        for (int r = 0; r < 4; ++r) {
            const int b = wb0 + quad * 4 + r;
            mbuf[ch * B_SZ + b] = m_r[r];
            lbuf[ch * B_SZ + b] = l_r[r];
        }
    }
}

__global__ __launch_bounds__(256) void attn_reduce(
    const float* __restrict__ mbuf, const float* __restrict__ lbuf,
    const int*   __restrict__ cntp, const float* __restrict__ obuf,
    float* __restrict__ out, int nz)
{
    const int b = blockIdx.x * 2 + (threadIdx.x >> 7);
    const int d = threadIdx.x & 127;

    float M = -1e30f;
    for (int c = 0; c < nz; ++c) M = fmaxf(M, mbuf[c * B_SZ + b]);

    float L = 0.f, acc = 0.f;
    for (int c = 0; c < nz; ++c) {
        float w = __expf(mbuf[c * B_SZ + b] - M);
        L += lbuf[c * B_SZ + b] * w;
        acc += obuf[((size_t)c * B_SZ + b) * D_SZ + d] * w;
    }
    float C = (float)(cntp[b*4] + cntp[b*4+1] + cntp[b*4+2] + cntp[b*4+3]);
    float cnt = fmaxf(C, 1.0f);
    out[(size_t)b * D_SZ + d] = (L > 0.f) ? acc / (L * cnt) : 0.f;
}

extern "C" void kernel_launch(void* const* d_in, const int* in_sizes, int n_in,
                              void* d_out, int out_size, void* d_ws, size_t ws_size,
                              hipStream_t stream) {
    (void)in_sizes; (void)n_in; (void)out_size;
    const int*   zs  = (const int*)  d_in[0];
    const float* ctx = (const float*)d_in[1];
    const float* emb = (const float*)d_in[2];
    float* out = (float*)d_out;
    float* wsf = (float*)d_ws;

    const size_t EMB_FL = (size_t)Z_SZ * D_SZ / 2;     // bf16 table, float units
    const size_t PK_FL  = (size_t)B_SZ * (Z_SZ / 32);  // u32 bitmask, float units
    const size_t CNT_FL = B_SZ;                        // [B][4] int -> B floats... (B*4 ints = B_SZ*4*4B)
    // nz by workspace budget (ws_size constant across calls)
    int nz = 64;
    {
        size_t need64 = (2 * EMB_FL + PK_FL + 4 * CNT_FL + (size_t)64 * B_SZ * (2 + D_SZ)) * 4;
        if (ws_size < need64) nz = 32;
    }
    const int iters = (Z_SZ / nz) / TZ;

    unsigned short* embB  = (unsigned short*)wsf;
    unsigned short* embT2 = (unsigned short*)(wsf + EMB_FL);
    unsigned*       pk    = (unsigned*)(wsf + 2 * EMB_FL);
    int*            cntp  = (int*)(wsf + 2 * EMB_FL + PK_FL);        // [B][4]
    float* mbuf = wsf + 2 * EMB_FL + PK_FL + 4 * CNT_FL;
    float* lbuf = mbuf + (size_t)nz * B_SZ;
    float* obuf = lbuf + (size_t)nz * B_SZ;

    convert_emb<<<Z_SZ / 64, 256, 0, stream>>>(emb, embB, embT2);
    pack_mask<<<B_SZ, 256, 0, stream>>>(zs, pk, cntp);

    dim3 grid1(nz, B_SZ / TBLK);   // chunk fastest -> per-XCD chunk affinity
    attn_part<<<grid1, 256, 0, stream>>>((const unsigned long long*)pk, ctx, embB, embT2,
                                         mbuf, lbuf, obuf, iters);

    attn_reduce<<<B_SZ / 2, 256, 0, stream>>>(mbuf, lbuf, cntp, obuf, out, nz);
}